// Round 13
// baseline (694.531 us; speedup 1.0000x reference)
//
#include <hip/hip_runtime.h>
#include <hip/hip_bf16.h>

// ============================================================================
// ASTRAMoE v13 = R12 with the REAL register cap fixed.
//   KEY FIX: HIP __launch_bounds__ 2nd arg is min BLOCKS/CU (CUDA semantics),
//   not waves/EU. (512,4) meant 4 blocks -> 8 waves/EU -> 64-VGPR cap -> R12's
//   gate epilogue spilled (FETCH+100MB, WRITE+195MB). (512,2) -> 128-VGPR cap;
//   LDS (65.6KB) already limits to 2 blocks/CU so zero occupancy cost.
//   - gate slot: fp32 register L2 (exact erf), DELTA=0.008 (tail 49us, R12).
//   - expert/alpha: hs dbuf 1 barrier/phase, key16 swizzle, w<4-only L2.
// d_out (fp32): logits[N*10] | alpha[N*10] | gate_weights[N*4] | load[4]
// ============================================================================

typedef _Float16 f16x8 __attribute__((ext_vector_type(8)));
typedef _Float16 f16x4 __attribute__((ext_vector_type(4)));
typedef float    f32x4 __attribute__((ext_vector_type(4)));

static constexpr int    NTOK      = 262144;
static constexpr size_t ALPHA_OFF = (size_t)NTOK * 10;
static constexpr size_t GW_OFF    = (size_t)2 * NTOK * 10;
static constexpr size_t LOAD_OFF  = GW_OFF + (size_t)NTOK * 4;

// ws layout (bytes)
static constexpr size_t W1F_OFF   = 0;          // 6*65536 halfs = 786432
static constexpr size_t W2F_OFF   = 786432;     // 6*4096 halfs  = 49152
static constexpr size_t CNT_OFF   = 835584;     // u32 counter (64 B slot)
static constexpr size_t LIST_OFF  = 835648;     // 262144 u32   = 1 MB
static constexpr size_t LPART_OFF = 1884224;    // 4096*4 f32   = 64 KB

static constexpr float DELTA = 0.008f;

__device__ __forceinline__ float gelu_exact(float v){
  return 0.5f * v * (1.0f + erff(v * 0.7071067811865475f));
}
__device__ __forceinline__ float gelu_fast(float v){
  float t = v * v;
  float p = __builtin_fmaf(0.0713548162726f, t, 1.5957691216057f);
  float z = __expf(v * p);
  float r = __builtin_amdgcn_rcpf(z + 1.0f);
  return v - v * r;
}
__device__ __forceinline__ float softplus_fast(float v){
  float z = __expf(v);
  float l = __logf(1.0f + z);
  return (v > 15.0f) ? v : l;
}
__device__ __forceinline__ f32x4 mfma16(f16x8 a, f16x8 b, f32x4 c){
  return __builtin_amdgcn_mfma_f32_16x16x32_f16(a, b, c, 0, 0, 0);
}
__device__ __forceinline__ f16x8 pk8(float4 a, float4 b){
  union { f16x8 v; unsigned u[4]; } r;
  r.u[0] = __builtin_bit_cast(unsigned, __builtin_amdgcn_cvt_pkrtz(a.x, a.y));
  r.u[1] = __builtin_bit_cast(unsigned, __builtin_amdgcn_cvt_pkrtz(a.z, a.w));
  r.u[2] = __builtin_bit_cast(unsigned, __builtin_amdgcn_cvt_pkrtz(b.x, b.y));
  r.u[3] = __builtin_bit_cast(unsigned, __builtin_amdgcn_cvt_pkrtz(b.z, b.w));
  return r.v;
}
__device__ __forceinline__ f16x4 pk4(float a, float b, float c, float d){
  union { f16x4 v; unsigned u[2]; } r;
  r.u[0] = __builtin_bit_cast(unsigned, __builtin_amdgcn_cvt_pkrtz(a, b));
  r.u[1] = __builtin_bit_cast(unsigned, __builtin_amdgcn_cvt_pkrtz(c, d));
  return r.v;
}

// exact top-2 (lowest index wins ties, matches jax.lax.top_k) + scatter-softmax
__device__ __forceinline__ void topk4(float v0, float v1, float v2, float v3,
                                      float4& gw, float& gap, int& i1, int& i2){
  float m1 = fmaxf(fmaxf(v0, v1), fmaxf(v2, v3));
  i1 = (v0 == m1) ? 0 : (v1 == m1) ? 1 : (v2 == m1) ? 2 : 3;
  float m2 = 0.f; i2 = -1;
  if (0 != i1){ m2 = v0; i2 = 0; }
  if (1 != i1 && (i2 < 0 || v1 > m2)){ m2 = v1; i2 = 1; }
  if (2 != i1 && (i2 < 0 || v2 > m2)){ m2 = v2; i2 = 2; }
  if (3 != i1 && (i2 < 0 || v3 > m2)){ m2 = v3; i2 = 3; }
  float m3 = -3.0e38f;
  if (0 != i1 && 0 != i2) m3 = fmaxf(m3, v0);
  if (1 != i1 && 1 != i2) m3 = fmaxf(m3, v1);
  if (2 != i1 && 2 != i2) m3 = fmaxf(m3, v2);
  if (3 != i1 && 3 != i2) m3 = fmaxf(m3, v3);
  gap = m2 - m3;
  float mm = fmaxf(m1, 0.0f);
  float s0 = (0 == i1 || 0 == i2) ? v0 : 0.0f;
  float s1 = (1 == i1 || 1 == i2) ? v1 : 0.0f;
  float s2 = (2 == i1 || 2 == i2) ? v2 : 0.0f;
  float s3 = (3 == i1 || 3 == i2) ? v3 : 0.0f;
  float e0 = expf(s0 - mm), e1 = expf(s1 - mm), e2 = expf(s2 - mm), e3 = expf(s3 - mm);
  float inv = 1.0f / (e0 + e1 + e2 + e3);
  gw.x = e0 * inv; gw.y = e1 * inv; gw.z = e2 * inv; gw.w = e3 * inv;
}

// ---------------------------------------------------------------------------
// prep: W1F frag-linear fp16 A-layout: [e(6)][kc(8)][ht(16)][lane(64)][8]
//   value = W1^T[h = ht*16 + (l&15)][d = kc*32 + (l>>4)*8 + j]
// ---------------------------------------------------------------------------
__global__ void prep_w1f(const float* __restrict__ We1, const float* __restrict__ Wa1,
                         const float* __restrict__ Wg1, _Float16* __restrict__ W1F){
  int idx = blockIdx.x * 256 + threadIdx.x;          // < 49152
  int e = idx >> 13;
  int r = idx & 8191;
  int kc = r >> 10;
  int entry = r & 1023;
  int ht = entry >> 6, ll = entry & 63;
  int h = ht * 16 + (ll & 15);
  int d0 = kc * 32 + ((ll >> 4) << 3);
  f16x8 o;
  #pragma unroll
  for (int j = 0; j < 8; ++j){
    int d = d0 + j;
    float v;
    if (e < 4)       v = We1[e * 65536 + d * 256 + h];
    else if (e == 4) v = Wa1[d * 256 + h];
    else             v = Wg1[d * 256 + h];
    o[j] = (_Float16)v;
  }
  *(f16x8*)&W1F[(size_t)idx * 8] = o;
}

// prep: W2F frag-linear fp16 A-layout: [e(6)][kc2(8)][lane(64)][8]; zero counter
__global__ void prep_w2f(const float* __restrict__ We2, const float* __restrict__ Wa2,
                         const float* __restrict__ Wg2, _Float16* __restrict__ W2F,
                         unsigned int* __restrict__ cntp){
  if (blockIdx.x == 0 && threadIdx.x == 0) *cntp = 0;
  int idx = blockIdx.x * 256 + threadIdx.x;          // < 3072
  int e = idx >> 9;
  int r = idx & 511;
  int k2 = r >> 6, ll = r & 63;
  int c = ll & 15;
  int h0 = k2 * 32 + ((ll >> 4) << 3);
  f16x8 o;
  #pragma unroll
  for (int j = 0; j < 8; ++j){
    int h = h0 + j;
    float v = 0.0f;
    if (e < 4){ if (c < 10) v = We2[e * 2560 + h * 10 + c]; }
    else if (e == 4){ if (c < 10) v = Wa2[h * 10 + c]; }
    else { if (c < 4) v = Wg2[h * 4 + c]; }
    o[j] = (_Float16)v;
  }
  *(f16x8*)&W2F[(size_t)idx * 8] = o;
}

// ---------------------------------------------------------------------------
// fused kernel. 512 threads (8 waves), 64 tokens/block, 4096 blocks.
// Wave w: L1 h-strip tiles {w, w+8} (32 h) over all 64 tokens (acc[2][4]).
// Gate slot: fp32 register L2 (exact erf) + 8-wave gred reduce (overlay hs0).
// Expert/alpha slots: hs dbuf, 1 barrier/phase; L2-consume on waves w<4 only.
// LDS: xs 32K | hs0 16K (gate: gred 8K) | hs1 16K | lsum = 65.6 KB -> 2/CU.
// ---------------------------------------------------------------------------
__device__ __forceinline__ void run_l1(const _Float16* __restrict__ w1s,
                                       const unsigned char* __restrict__ xsb,
                                       int w, int l, int l15, int lq,
                                       f32x4 acc[2][4]){
  #pragma unroll
  for (int kc = 0; kc < 8; ++kc){
    f16x8 af[2], bf[4];
    #pragma unroll
    for (int i = 0; i < 2; ++i)
      af[i] = *(const f16x8*)&w1s[(size_t)kc * 8192 + (w + 8 * i) * 512 + l * 8];
    #pragma unroll
    for (int tt = 0; tt < 4; ++tt){
      int lt = tt * 16 + l15;
      bf[tt] = *(const f16x8*)(xsb + lt * 512 +
                 ((kc * 64 + lq * 16) ^ ((lt & 15) << 4)));
    }
    __builtin_amdgcn_s_setprio(1);
    #pragma unroll
    for (int i = 0; i < 2; ++i)
      #pragma unroll
      for (int tt = 0; tt < 4; ++tt)
        acc[i][tt] = mfma16(af[i], bf[tt], acc[i][tt]);
    __builtin_amdgcn_s_setprio(0);
  }
}

__global__ __launch_bounds__(512, 2) void fused_kernel(
    const float* __restrict__ x,
    const _Float16* __restrict__ W1F, const _Float16* __restrict__ W2F,
    const float* __restrict__ bg1, const float* __restrict__ Wg2,
    const float* __restrict__ bg2,
    const float* __restrict__ be1, const float* __restrict__ be2,
    const float* __restrict__ ba1, const float* __restrict__ ba2,
    float* __restrict__ out, unsigned int* __restrict__ list,
    unsigned int* __restrict__ cntp, float* __restrict__ lpart){
  __shared__ __align__(16) unsigned char lds[65600];
  unsigned char* xsb = lds;                         // 32 KB [64 tok][512 B]
  unsigned char* hs0 = lds + 32768;                 // 16 KB (phase 0)
  unsigned char* hs1 = lds + 49152;                 // 16 KB (phase 1)
  float*        gred = (float*)(lds + 32768);       // 8 KB (gate only, over hs0)
  float*        lsum = (float*)(lds + 65536);       // 16 floats

  const int tid = threadIdx.x;
  const int w = tid >> 6, l = tid & 63;
  const int l15 = l & 15, lq = l >> 4;
  const size_t t0 = (size_t)blockIdx.x * 64;
  const int tokL = (w & 3) * 16 + l15;              // L2 token within block
  const int key  = (tokL & 15) << 4;

  // ---- stage x -> fp16 swizzled LDS (coalesced 32B/lane loads) ----
  {
    int d = (tid & 31) * 8;
    #pragma unroll
    for (int q = 0; q < 4; ++q){
      int tk = q * 16 + (tid >> 5);
      const float* xp = x + (t0 + tk) * 256 + d;
      float4 f0 = *(const float4*)xp;
      float4 f1 = *(const float4*)(xp + 4);
      *(f16x8*)(xsb + tk * 512 + ((d * 2) ^ ((tk & 15) << 4))) = pk8(f0, f1);
    }
  }
  __syncthreads();

  f32x4 lacc = {0,0,0,0};
  float4 gw4 = {0,0,0,0};

  // ================= GATE slot (fp32 register L2, exact erf) =================
  {
    f32x4 acc[2][4];
    #pragma unroll
    for (int i = 0; i < 2; ++i)
      #pragma unroll
      for (int tt = 0; tt < 4; ++tt){
        acc[i][tt][0]=0.f; acc[i][tt][1]=0.f; acc[i][tt][2]=0.f; acc[i][tt][3]=0.f;
      }
    run_l1(W1F + (size_t)5 * 65536, xsb, w, l, l15, lq, acc);

    float gp[4][4];
    #pragma unroll
    for (int tt = 0; tt < 4; ++tt){ gp[tt][0]=0.f; gp[tt][1]=0.f; gp[tt][2]=0.f; gp[tt][3]=0.f; }
    #pragma unroll
    for (int i = 0; i < 2; ++i){
      int hbase = (w + 8 * i) * 16 + lq * 4;
      float4 b4 = *(const float4*)&bg1[hbase];
      float bb[4] = {b4.x, b4.y, b4.z, b4.w};
      #pragma unroll
      for (int r = 0; r < 4; ++r){
        float4 w2 = *(const float4*)&Wg2[(hbase + r) * 4];
        #pragma unroll
        for (int tt = 0; tt < 4; ++tt){
          float g = gelu_exact(acc[i][tt][r] + bb[r]);
          gp[tt][0] += g * w2.x; gp[tt][1] += g * w2.y;
          gp[tt][2] += g * w2.z; gp[tt][3] += g * w2.w;
        }
      }
    }
    // reduce over lq within wave (lanes 0..15 end with the wave partial)
    #pragma unroll
    for (int tt = 0; tt < 4; ++tt)
      #pragma unroll
      for (int c = 0; c < 4; ++c){
        gp[tt][c] += __shfl_xor(gp[tt][c], 16, 64);
        gp[tt][c] += __shfl_xor(gp[tt][c], 32, 64);
      }
    if (lq == 0){
      #pragma unroll
      for (int tt = 0; tt < 4; ++tt){
        float4 v; v.x = gp[tt][0]; v.y = gp[tt][1]; v.z = gp[tt][2]; v.w = gp[tt][3];
        *(float4*)&gred[(w * 64 + tt * 16 + l15) * 4] = v;
      }
    }
    __syncthreads();    // all gred partials visible

    float4 gw = {0,0,0,0};
    float4 lgw = {0,0,0,0};
    int i1 = 0, i2 = 0;
    bool flagged = false;
    if (lq == 0 && w < 4){
      float v0 = bg2[0], v1 = bg2[1], v2 = bg2[2], v3 = bg2[3];
      #pragma unroll
      for (int ww = 0; ww < 8; ++ww){
        float4 s = *(const float4*)&gred[(ww * 64 + tokL) * 4];
        v0 += s.x; v1 += s.y; v2 += s.z; v3 += s.w;
      }
      float gap;
      topk4(v0, v1, v2, v3, gw, gap, i1, i2);
      size_t t = t0 + tokL;
      *(float4*)&out[GW_OFF + t * 4] = gw;
      flagged = (gap < DELTA);
      lgw = gw;
    }
    // broadcast token's gw to all lanes of the wave (valid on w<4)
    gw4.x = __shfl(gw.x, l15, 64);
    gw4.y = __shfl(gw.y, l15, 64);
    gw4.z = __shfl(gw.z, l15, 64);
    gw4.w = __shfl(gw.w, l15, 64);
    if (w < 4){
      // compact flagged tokens into global list (wave-level)
      unsigned long long m = __ballot(flagged);
      int cnt = __popcll(m);
      if (cnt){
        unsigned base = 0;
        if (l == 0) base = atomicAdd(cntp, (unsigned)cnt);
        base = __shfl(base, 0, 64);
        if (flagged){
          unsigned rank = (unsigned)__popcll(m & ((1ull << l) - 1ull));
          list[base + rank] = (unsigned)(t0 + tokL) | (i1 << 18) | (i2 << 20);
        }
      }
      // block-local load partial
      #pragma unroll
      for (int mm = 1; mm < 64; mm <<= 1){
        lgw.x += __shfl_xor(lgw.x, mm, 64); lgw.y += __shfl_xor(lgw.y, mm, 64);
        lgw.z += __shfl_xor(lgw.z, mm, 64); lgw.w += __shfl_xor(lgw.w, mm, 64);
      }
      if (l == 0) *(float4*)&lsum[w * 4] = lgw;
    }
    __syncthreads();    // lsum ready; also gred dead before hs0 reuse
    if (tid < 4)
      lpart[(size_t)blockIdx.x * 4 + tid] =
          lsum[tid] + lsum[4 + tid] + lsum[8 + tid] + lsum[12 + tid];
  }

  // ================= experts 0..3 + alpha (slot 4) =================
  #pragma unroll 1
  for (int e = 0; e < 5; ++e){
    f32x4 acc[2][4];
    #pragma unroll
    for (int i = 0; i < 2; ++i)
      #pragma unroll
      for (int tt = 0; tt < 4; ++tt){
        acc[i][tt][0]=0.f; acc[i][tt][1]=0.f; acc[i][tt][2]=0.f; acc[i][tt][3]=0.f;
      }
    run_l1(W1F + (size_t)e * 65536, xsb, w, l, l15, lq, acc);

    const float* b1p = (e < 4) ? (be1 + e * 256) : ba1;
    f32x4 d2 = {0,0,0,0};
    #pragma unroll
    for (int p = 0; p < 2; ++p){
      unsigned char* hb_ = p ? hs1 : hs0;
      {
        int hb = (w + 8 * p) * 16 + lq * 4;     // global h base (strip i=p)
        float4 b4 = *(const float4*)&b1p[hb];
        int lb = (w * 16 + lq * 4) * 2;         // local byte col
        #pragma unroll
        for (int tt = 0; tt < 4; ++tt){
          f16x4 hv = pk4(gelu_fast(acc[p][tt][0] + b4.x),
                         gelu_fast(acc[p][tt][1] + b4.y),
                         gelu_fast(acc[p][tt][2] + b4.z),
                         gelu_fast(acc[p][tt][3] + b4.w));
          int lt = tt * 16 + l15;
          *(f16x4*)(hb_ + lt * 256 + (lb ^ ((lt & 15) << 4))) = hv;
        }
      }
      __syncthreads();   // buf p ready; also orders last-read vs next-write
      if (w < 4){
        #pragma unroll
        for (int k2h = 0; k2h < 4; ++k2h){
          int k2 = 4 * p + k2h;
          f16x8 a2 = *(const f16x8*)&W2F[((size_t)(e * 8 + k2) * 64 + l) * 8];
          f16x8 b2 = *(const f16x8*)(hb_ + tokL * 256 + ((k2h * 64 + lq * 16) ^ key));
          d2 = mfma16(a2, b2, d2);
        }
      }
      // no trailing barrier: next write to this buffer is 2 phases away.
    }

    if (e < 4){
      if (w < 4){
        float gwv = (e == 0) ? gw4.x : (e == 1) ? gw4.y : (e == 2) ? gw4.z : gw4.w;
        #pragma unroll
        for (int r = 0; r < 4; ++r){
          int c = lq * 4 + r;
          float bv = (c < 10) ? be2[e * 10 + c] : 0.0f;
          lacc[r] += gwv * (d2[r] + bv);
        }
      }
    } else {
      if (w < 4){
        size_t t = t0 + tokL;
        #pragma unroll
        for (int r = 0; r < 4; ++r){
          int c = lq * 4 + r;
          if (c < 10)
            out[ALPHA_OFF + t * 10 + c] = softplus_fast(d2[r] + ba2[c]) + 1e-6f;
        }
      }
    }
  }
  // final logits write
  if (w < 4){
    size_t t = t0 + tokL;
    #pragma unroll
    for (int r = 0; r < 4; ++r){
      int c = lq * 4 + r;
      if (c < 10) out[t * 10 + c] = lacc[r];
    }
  }
}

// ---------------------------------------------------------------------------
// refine (R8 version): exact fp32 gate for listed tokens; on selection flip
// also recompute logits (all 4 experts, exact gw).
// ---------------------------------------------------------------------------
__global__ __launch_bounds__(256) void refine_kernel(
    const float* __restrict__ x, const float* __restrict__ Wg1,
    const float* __restrict__ bg1, const float* __restrict__ Wg2,
    const float* __restrict__ bg2,
    const float* __restrict__ We1, const float* __restrict__ be1,
    const float* __restrict__ We2, const float* __restrict__ be2,
    const unsigned int* __restrict__ list, const unsigned int* __restrict__ cntp,
    float* __restrict__ out){
  int cnt = (int)*cntp;
  int l = threadIdx.x & 63;
  int hb = l * 4;
  for (int idx = blockIdx.x * 4 + (threadIdx.x >> 6); idx < cnt;
       idx += gridDim.x * 4){
    unsigned ent = list[idx];
    int t = (int)(ent & 0x3FFFFu);
    int oi1 = (ent >> 18) & 3, oi2 = (ent >> 20) & 3;
    const float* xr = x + (size_t)t * 256;
    float a0 = 0.f, a1 = 0.f, a2 = 0.f, a3 = 0.f;
    #pragma unroll 8
    for (int d = 0; d < 256; ++d){
      float xv = xr[d];
      float4 wv = *(const float4*)&Wg1[d * 256 + hb];
      a0 = fmaf(xv, wv.x, a0); a1 = fmaf(xv, wv.y, a1);
      a2 = fmaf(xv, wv.z, a2); a3 = fmaf(xv, wv.w, a3);
    }
    float4 b4 = *(const float4*)&bg1[hb];
    float g0 = gelu_exact(a0 + b4.x), g1 = gelu_exact(a1 + b4.y);
    float g2 = gelu_exact(a2 + b4.z), g3 = gelu_exact(a3 + b4.w);
    float4 w0 = *(const float4*)&Wg2[(hb + 0) * 4];
    float4 w1 = *(const float4*)&Wg2[(hb + 1) * 4];
    float4 w2 = *(const float4*)&Wg2[(hb + 2) * 4];
    float4 w3 = *(const float4*)&Wg2[(hb + 3) * 4];
    float p0 = g0 * w0.x + g1 * w1.x + g2 * w2.x + g3 * w3.x;
    float p1 = g0 * w0.y + g1 * w1.y + g2 * w2.y + g3 * w3.y;
    float p2 = g0 * w0.z + g1 * w1.z + g2 * w2.z + g3 * w3.z;
    float p3 = g0 * w0.w + g1 * w1.w + g2 * w2.w + g3 * w3.w;
    #pragma unroll
    for (int m = 1; m < 64; m <<= 1){
      p0 += __shfl_xor(p0, m, 64); p1 += __shfl_xor(p1, m, 64);
      p2 += __shfl_xor(p2, m, 64); p3 += __shfl_xor(p3, m, 64);
    }
    float4 gw; float gap; int i1, i2;
    topk4(p0 + bg2[0], p1 + bg2[1], p2 + bg2[2], p3 + bg2[3], gw, gap, i1, i2);
    if (l == 0) *(float4*)&out[GW_OFF + (size_t)t * 4] = gw;
    int oldset = (1 << oi1) | (1 << oi2);
    int newset = (1 << i1) | (1 << i2);
    if (oldset != newset){
      float lg[10];
      #pragma unroll
      for (int c = 0; c < 10; ++c) lg[c] = 0.f;
      for (int e = 0; e < 4; ++e){
        float gwe = (e == 0) ? gw.x : (e == 1) ? gw.y : (e == 2) ? gw.z : gw.w;
        float c0 = 0.f, c1 = 0.f, c2 = 0.f, c3 = 0.f;
        #pragma unroll 8
        for (int d = 0; d < 256; ++d){
          float xv = xr[d];
          float4 wv = *(const float4*)&We1[e * 65536 + d * 256 + hb];
          c0 = fmaf(xv, wv.x, c0); c1 = fmaf(xv, wv.y, c1);
          c2 = fmaf(xv, wv.z, c2); c3 = fmaf(xv, wv.w, c3);
        }
        float4 be = *(const float4*)&be1[e * 256 + hb];
        float h[4];
        h[0] = gelu_exact(c0 + be.x); h[1] = gelu_exact(c1 + be.y);
        h[2] = gelu_exact(c2 + be.z); h[3] = gelu_exact(c3 + be.w);
        #pragma unroll
        for (int r = 0; r < 4; ++r){
          const float* w2p = &We2[e * 2560 + (hb + r) * 10];
          #pragma unroll
          for (int c = 0; c < 10; ++c) lg[c] += gwe * (h[r] * w2p[c]);
        }
      }
      #pragma unroll
      for (int m = 1; m < 64; m <<= 1)
        #pragma unroll
        for (int c = 0; c < 10; ++c) lg[c] += __shfl_xor(lg[c], m, 64);
      if (l == 0){
        #pragma unroll
        for (int c = 0; c < 10; ++c)
          out[(size_t)t * 10 + c] = lg[c] + gw.x * be2[c] + gw.y * be2[10 + c]
                                         + gw.z * be2[20 + c] + gw.w * be2[30 + c];
      }
    }
  }
}

// coalesced deterministic reduce of 4096x4 partials -> load[4]
__global__ void reduce_load(const float* __restrict__ lpart, float* __restrict__ out){
  __shared__ float red[4][4];
  int tid = threadIdx.x;
  const float4* lp = (const float4*)lpart;
  float4 v = {0,0,0,0};
  #pragma unroll
  for (int j = 0; j < 16; ++j){
    float4 t = lp[tid + 256 * j];
    v.x += t.x; v.y += t.y; v.z += t.z; v.w += t.w;
  }
  #pragma unroll
  for (int m = 1; m < 64; m <<= 1){
    v.x += __shfl_xor(v.x, m, 64); v.y += __shfl_xor(v.y, m, 64);
    v.z += __shfl_xor(v.z, m, 64); v.w += __shfl_xor(v.w, m, 64);
  }
  if ((tid & 63) == 0){
    red[tid >> 6][0] = v.x; red[tid >> 6][1] = v.y;
    red[tid >> 6][2] = v.z; red[tid >> 6][3] = v.w;
  }
  __syncthreads();
  if (tid < 4)
    out[LOAD_OFF + tid] = red[0][tid] + red[1][tid] + red[2][tid] + red[3][tid];
}

// ---------------------------------------------------------------------------
extern "C" void kernel_launch(void* const* d_in, const int* in_sizes, int n_in,
                              void* d_out, int out_size, void* d_ws, size_t ws_size,
                              hipStream_t stream){
  const float* x   = (const float*)d_in[0];
  const float* Wg1 = (const float*)d_in[1];
  const float* bg1 = (const float*)d_in[2];
  const float* Wg2 = (const float*)d_in[3];
  const float* bg2 = (const float*)d_in[4];
  const float* We1 = (const float*)d_in[5];
  const float* be1 = (const float*)d_in[6];
  const float* We2 = (const float*)d_in[7];
  const float* be2 = (const float*)d_in[8];
  const float* Wa1 = (const float*)d_in[9];
  const float* ba1 = (const float*)d_in[10];
  const float* Wa2 = (const float*)d_in[11];
  const float* ba2 = (const float*)d_in[12];
  float* out = (float*)d_out;

  _Float16* W1F       = (_Float16*)((char*)d_ws + W1F_OFF);
  _Float16* W2F       = (_Float16*)((char*)d_ws + W2F_OFF);
  unsigned int* cntp  = (unsigned int*)((char*)d_ws + CNT_OFF);
  unsigned int* list  = (unsigned int*)((char*)d_ws + LIST_OFF);
  float* lpart        = (float*)((char*)d_ws + LPART_OFF);

  hipLaunchKernelGGL(prep_w1f, dim3(192), dim3(256), 0, stream, We1, Wa1, Wg1, W1F);
  hipLaunchKernelGGL(prep_w2f, dim3(12),  dim3(256), 0, stream, We2, Wa2, Wg2, W2F, cntp);
  hipLaunchKernelGGL(fused_kernel, dim3(4096), dim3(512), 0, stream,
                     x, W1F, W2F, bg1, Wg2, bg2, be1, be2, ba1, ba2,
                     out, list, cntp, lpart);
  hipLaunchKernelGGL(refine_kernel, dim3(1024), dim3(256), 0, stream,
                     x, Wg1, bg1, Wg2, bg2, We1, be1, We2, be2, list, cntp, out);
  hipLaunchKernelGGL(reduce_load, dim3(1), dim3(256), 0, stream, lpart, out);
}

// Round 14
// 507.999 us; speedup vs baseline: 1.3672x; 1.3672x over previous
//
#include <hip/hip_runtime.h>
#include <hip/hip_bf16.h>

// ============================================================================
// ASTRAMoE v14 = R12 precise-gate, refit into the 64-VGPR envelope.
//   - launch_bounds(512,4): the ONLY config with 2-block/CU residency
//     (R13: giving 128 regs dropped residency to 1 block -> 1.6x slower).
//   - gate epilogue restructured per-tt: 4-reg gpl streamed to gred, acc
//     consumed tile-by-tile -> peak live ~55 regs, fits the 64 cap.
//   - DELTA=0.008 (precise fp32-erf gate logits) -> refine tail ~49us (R12).
//   - expert/alpha slots: hs dbuf 1 barrier/phase, key16 swizzle, w<4 L2.
// d_out (fp32): logits[N*10] | alpha[N*10] | gate_weights[N*4] | load[4]
// ============================================================================

typedef _Float16 f16x8 __attribute__((ext_vector_type(8)));
typedef _Float16 f16x4 __attribute__((ext_vector_type(4)));
typedef float    f32x4 __attribute__((ext_vector_type(4)));

static constexpr int    NTOK      = 262144;
static constexpr size_t ALPHA_OFF = (size_t)NTOK * 10;
static constexpr size_t GW_OFF    = (size_t)2 * NTOK * 10;
static constexpr size_t LOAD_OFF  = GW_OFF + (size_t)NTOK * 4;

// ws layout (bytes)
static constexpr size_t W1F_OFF   = 0;          // 6*65536 halfs = 786432
static constexpr size_t W2F_OFF   = 786432;     // 6*4096 halfs  = 49152
static constexpr size_t CNT_OFF   = 835584;     // u32 counter (64 B slot)
static constexpr size_t LIST_OFF  = 835648;     // 262144 u32   = 1 MB
static constexpr size_t LPART_OFF = 1884224;    // 4096*4 f32   = 64 KB

static constexpr float DELTA = 0.008f;

__device__ __forceinline__ float gelu_exact(float v){
  return 0.5f * v * (1.0f + erff(v * 0.7071067811865475f));
}
__device__ __forceinline__ float gelu_fast(float v){
  float t = v * v;
  float p = __builtin_fmaf(0.0713548162726f, t, 1.5957691216057f);
  float z = __expf(v * p);
  float r = __builtin_amdgcn_rcpf(z + 1.0f);
  return v - v * r;
}
__device__ __forceinline__ float softplus_fast(float v){
  float z = __expf(v);
  float l = __logf(1.0f + z);
  return (v > 15.0f) ? v : l;
}
__device__ __forceinline__ f32x4 mfma16(f16x8 a, f16x8 b, f32x4 c){
  return __builtin_amdgcn_mfma_f32_16x16x32_f16(a, b, c, 0, 0, 0);
}
__device__ __forceinline__ f16x8 pk8(float4 a, float4 b){
  union { f16x8 v; unsigned u[4]; } r;
  r.u[0] = __builtin_bit_cast(unsigned, __builtin_amdgcn_cvt_pkrtz(a.x, a.y));
  r.u[1] = __builtin_bit_cast(unsigned, __builtin_amdgcn_cvt_pkrtz(a.z, a.w));
  r.u[2] = __builtin_bit_cast(unsigned, __builtin_amdgcn_cvt_pkrtz(b.x, b.y));
  r.u[3] = __builtin_bit_cast(unsigned, __builtin_amdgcn_cvt_pkrtz(b.z, b.w));
  return r.v;
}
__device__ __forceinline__ f16x4 pk4(float a, float b, float c, float d){
  union { f16x4 v; unsigned u[2]; } r;
  r.u[0] = __builtin_bit_cast(unsigned, __builtin_amdgcn_cvt_pkrtz(a, b));
  r.u[1] = __builtin_bit_cast(unsigned, __builtin_amdgcn_cvt_pkrtz(c, d));
  return r.v;
}

// exact top-2 (lowest index wins ties, matches jax.lax.top_k) + scatter-softmax
__device__ __forceinline__ void topk4(float v0, float v1, float v2, float v3,
                                      float4& gw, float& gap, int& i1, int& i2){
  float m1 = fmaxf(fmaxf(v0, v1), fmaxf(v2, v3));
  i1 = (v0 == m1) ? 0 : (v1 == m1) ? 1 : (v2 == m1) ? 2 : 3;
  float m2 = 0.f; i2 = -1;
  if (0 != i1){ m2 = v0; i2 = 0; }
  if (1 != i1 && (i2 < 0 || v1 > m2)){ m2 = v1; i2 = 1; }
  if (2 != i1 && (i2 < 0 || v2 > m2)){ m2 = v2; i2 = 2; }
  if (3 != i1 && (i2 < 0 || v3 > m2)){ m2 = v3; i2 = 3; }
  float m3 = -3.0e38f;
  if (0 != i1 && 0 != i2) m3 = fmaxf(m3, v0);
  if (1 != i1 && 1 != i2) m3 = fmaxf(m3, v1);
  if (2 != i1 && 2 != i2) m3 = fmaxf(m3, v2);
  if (3 != i1 && 3 != i2) m3 = fmaxf(m3, v3);
  gap = m2 - m3;
  float mm = fmaxf(m1, 0.0f);
  float s0 = (0 == i1 || 0 == i2) ? v0 : 0.0f;
  float s1 = (1 == i1 || 1 == i2) ? v1 : 0.0f;
  float s2 = (2 == i1 || 2 == i2) ? v2 : 0.0f;
  float s3 = (3 == i1 || 3 == i2) ? v3 : 0.0f;
  float e0 = expf(s0 - mm), e1 = expf(s1 - mm), e2 = expf(s2 - mm), e3 = expf(s3 - mm);
  float inv = 1.0f / (e0 + e1 + e2 + e3);
  gw.x = e0 * inv; gw.y = e1 * inv; gw.z = e2 * inv; gw.w = e3 * inv;
}

// ---------------------------------------------------------------------------
// prep: W1F frag-linear fp16 A-layout: [e(6)][kc(8)][ht(16)][lane(64)][8]
//   value = W1^T[h = ht*16 + (l&15)][d = kc*32 + (l>>4)*8 + j]
// ---------------------------------------------------------------------------
__global__ void prep_w1f(const float* __restrict__ We1, const float* __restrict__ Wa1,
                         const float* __restrict__ Wg1, _Float16* __restrict__ W1F){
  int idx = blockIdx.x * 256 + threadIdx.x;          // < 49152
  int e = idx >> 13;
  int r = idx & 8191;
  int kc = r >> 10;
  int entry = r & 1023;
  int ht = entry >> 6, ll = entry & 63;
  int h = ht * 16 + (ll & 15);
  int d0 = kc * 32 + ((ll >> 4) << 3);
  f16x8 o;
  #pragma unroll
  for (int j = 0; j < 8; ++j){
    int d = d0 + j;
    float v;
    if (e < 4)       v = We1[e * 65536 + d * 256 + h];
    else if (e == 4) v = Wa1[d * 256 + h];
    else             v = Wg1[d * 256 + h];
    o[j] = (_Float16)v;
  }
  *(f16x8*)&W1F[(size_t)idx * 8] = o;
}

// prep: W2F frag-linear fp16 A-layout: [e(6)][kc2(8)][lane(64)][8]; zero counter
__global__ void prep_w2f(const float* __restrict__ We2, const float* __restrict__ Wa2,
                         const float* __restrict__ Wg2, _Float16* __restrict__ W2F,
                         unsigned int* __restrict__ cntp){
  if (blockIdx.x == 0 && threadIdx.x == 0) *cntp = 0;
  int idx = blockIdx.x * 256 + threadIdx.x;          // < 3072
  int e = idx >> 9;
  int r = idx & 511;
  int k2 = r >> 6, ll = r & 63;
  int c = ll & 15;
  int h0 = k2 * 32 + ((ll >> 4) << 3);
  f16x8 o;
  #pragma unroll
  for (int j = 0; j < 8; ++j){
    int h = h0 + j;
    float v = 0.0f;
    if (e < 4){ if (c < 10) v = We2[e * 2560 + h * 10 + c]; }
    else if (e == 4){ if (c < 10) v = Wa2[h * 10 + c]; }
    else { if (c < 4) v = Wg2[h * 4 + c]; }
    o[j] = (_Float16)v;
  }
  *(f16x8*)&W2F[(size_t)idx * 8] = o;
}

// ---------------------------------------------------------------------------
// fused kernel. 512 threads (8 waves), 64 tokens/block, 4096 blocks.
// Wave w: L1 h-strip tiles {w, w+8} (32 h) over all 64 tokens (acc[2][4]).
// Gate slot: fp32 register L2 (exact erf), computed PER-TT (low reg pressure)
//   -> gred (overlay hs0) -> topk; flag gap<DELTA.
// Expert/alpha slots: hs dbuf, 1 barrier/phase; L2-consume on waves w<4 only.
// LDS: xs 32K | hs0 16K (gate: gred 8K) | hs1 16K | lsum = 65.6 KB -> 2/CU.
// ---------------------------------------------------------------------------
__device__ __forceinline__ void run_l1(const _Float16* __restrict__ w1s,
                                       const unsigned char* __restrict__ xsb,
                                       int w, int l, int l15, int lq,
                                       f32x4 acc[2][4]){
  #pragma unroll
  for (int kc = 0; kc < 8; ++kc){
    f16x8 af[2], bf[4];
    #pragma unroll
    for (int i = 0; i < 2; ++i)
      af[i] = *(const f16x8*)&w1s[(size_t)kc * 8192 + (w + 8 * i) * 512 + l * 8];
    #pragma unroll
    for (int tt = 0; tt < 4; ++tt){
      int lt = tt * 16 + l15;
      bf[tt] = *(const f16x8*)(xsb + lt * 512 +
                 ((kc * 64 + lq * 16) ^ ((lt & 15) << 4)));
    }
    __builtin_amdgcn_s_setprio(1);
    #pragma unroll
    for (int i = 0; i < 2; ++i)
      #pragma unroll
      for (int tt = 0; tt < 4; ++tt)
        acc[i][tt] = mfma16(af[i], bf[tt], acc[i][tt]);
    __builtin_amdgcn_s_setprio(0);
  }
}

__global__ __launch_bounds__(512, 4) void fused_kernel(
    const float* __restrict__ x,
    const _Float16* __restrict__ W1F, const _Float16* __restrict__ W2F,
    const float* __restrict__ bg1, const float* __restrict__ Wg2,
    const float* __restrict__ bg2,
    const float* __restrict__ be1, const float* __restrict__ be2,
    const float* __restrict__ ba1, const float* __restrict__ ba2,
    float* __restrict__ out, unsigned int* __restrict__ list,
    unsigned int* __restrict__ cntp, float* __restrict__ lpart){
  __shared__ __align__(16) unsigned char lds[65600];
  unsigned char* xsb = lds;                         // 32 KB [64 tok][512 B]
  unsigned char* hs0 = lds + 32768;                 // 16 KB (phase 0)
  unsigned char* hs1 = lds + 49152;                 // 16 KB (phase 1)
  float*        gred = (float*)(lds + 32768);       // 8 KB (gate only, over hs0)
  float*        lsum = (float*)(lds + 65536);       // 16 floats

  const int tid = threadIdx.x;
  const int w = tid >> 6, l = tid & 63;
  const int l15 = l & 15, lq = l >> 4;
  const size_t t0 = (size_t)blockIdx.x * 64;
  const int tokL = (w & 3) * 16 + l15;              // L2 token within block
  const int key  = (tokL & 15) << 4;

  // ---- stage x -> fp16 swizzled LDS (coalesced 32B/lane loads) ----
  {
    int d = (tid & 31) * 8;
    #pragma unroll
    for (int q = 0; q < 4; ++q){
      int tk = q * 16 + (tid >> 5);
      const float* xp = x + (t0 + tk) * 256 + d;
      float4 f0 = *(const float4*)xp;
      float4 f1 = *(const float4*)(xp + 4);
      *(f16x8*)(xsb + tk * 512 + ((d * 2) ^ ((tk & 15) << 4))) = pk8(f0, f1);
    }
  }
  __syncthreads();

  f32x4 lacc = {0,0,0,0};
  float4 gw4 = {0,0,0,0};

  // ================= GATE slot (fp32 per-tt register L2, exact erf) =========
  {
    f32x4 acc[2][4];
    #pragma unroll
    for (int i = 0; i < 2; ++i)
      #pragma unroll
      for (int tt = 0; tt < 4; ++tt){
        acc[i][tt][0]=0.f; acc[i][tt][1]=0.f; acc[i][tt][2]=0.f; acc[i][tt][3]=0.f;
      }
    run_l1(W1F + (size_t)5 * 65536, xsb, w, l, l15, lq, acc);

    // per-tt epilogue: only 4 partial regs live at a time (fits 64-VGPR cap)
    #pragma unroll
    for (int tt = 0; tt < 4; ++tt){
      float gpl0 = 0.f, gpl1 = 0.f, gpl2 = 0.f, gpl3 = 0.f;
      #pragma unroll
      for (int i = 0; i < 2; ++i){
        int hbase = (w + 8 * i) * 16 + lq * 4;
        float4 b4 = *(const float4*)&bg1[hbase];
        float bb[4] = {b4.x, b4.y, b4.z, b4.w};
        #pragma unroll
        for (int r = 0; r < 4; ++r){
          float4 w2 = *(const float4*)&Wg2[(hbase + r) * 4];
          float g = gelu_exact(acc[i][tt][r] + bb[r]);
          gpl0 += g * w2.x; gpl1 += g * w2.y;
          gpl2 += g * w2.z; gpl3 += g * w2.w;
        }
      }
      gpl0 += __shfl_xor(gpl0, 16, 64); gpl0 += __shfl_xor(gpl0, 32, 64);
      gpl1 += __shfl_xor(gpl1, 16, 64); gpl1 += __shfl_xor(gpl1, 32, 64);
      gpl2 += __shfl_xor(gpl2, 16, 64); gpl2 += __shfl_xor(gpl2, 32, 64);
      gpl3 += __shfl_xor(gpl3, 16, 64); gpl3 += __shfl_xor(gpl3, 32, 64);
      if (lq == 0){
        float4 v; v.x = gpl0; v.y = gpl1; v.z = gpl2; v.w = gpl3;
        *(float4*)&gred[(w * 64 + tt * 16 + l15) * 4] = v;
      }
    }
    __syncthreads();    // all gred partials visible

    float4 gw = {0,0,0,0};
    float4 lgw = {0,0,0,0};
    int i1 = 0, i2 = 0;
    bool flagged = false;
    if (lq == 0 && w < 4){
      float v0 = bg2[0], v1 = bg2[1], v2 = bg2[2], v3 = bg2[3];
      #pragma unroll
      for (int ww = 0; ww < 8; ++ww){
        float4 s = *(const float4*)&gred[(ww * 64 + tokL) * 4];
        v0 += s.x; v1 += s.y; v2 += s.z; v3 += s.w;
      }
      float gap;
      topk4(v0, v1, v2, v3, gw, gap, i1, i2);
      size_t t = t0 + tokL;
      *(float4*)&out[GW_OFF + t * 4] = gw;
      flagged = (gap < DELTA);
      lgw = gw;
    }
    // broadcast token's gw to all lanes of the wave (valid on w<4)
    gw4.x = __shfl(gw.x, l15, 64);
    gw4.y = __shfl(gw.y, l15, 64);
    gw4.z = __shfl(gw.z, l15, 64);
    gw4.w = __shfl(gw.w, l15, 64);
    if (w < 4){
      // compact flagged tokens into global list (wave-level)
      unsigned long long m = __ballot(flagged);
      int cnt = __popcll(m);
      if (cnt){
        unsigned base = 0;
        if (l == 0) base = atomicAdd(cntp, (unsigned)cnt);
        base = __shfl(base, 0, 64);
        if (flagged){
          unsigned rank = (unsigned)__popcll(m & ((1ull << l) - 1ull));
          list[base + rank] = (unsigned)(t0 + tokL) | (i1 << 18) | (i2 << 20);
        }
      }
      // block-local load partial
      #pragma unroll
      for (int mm = 1; mm < 64; mm <<= 1){
        lgw.x += __shfl_xor(lgw.x, mm, 64); lgw.y += __shfl_xor(lgw.y, mm, 64);
        lgw.z += __shfl_xor(lgw.z, mm, 64); lgw.w += __shfl_xor(lgw.w, mm, 64);
      }
      if (l == 0) *(float4*)&lsum[w * 4] = lgw;
    }
    __syncthreads();    // lsum ready; also gred dead before hs0 reuse
    if (tid < 4)
      lpart[(size_t)blockIdx.x * 4 + tid] =
          lsum[tid] + lsum[4 + tid] + lsum[8 + tid] + lsum[12 + tid];
  }

  // ================= experts 0..3 + alpha (slot 4) =================
  #pragma unroll 1
  for (int e = 0; e < 5; ++e){
    f32x4 acc[2][4];
    #pragma unroll
    for (int i = 0; i < 2; ++i)
      #pragma unroll
      for (int tt = 0; tt < 4; ++tt){
        acc[i][tt][0]=0.f; acc[i][tt][1]=0.f; acc[i][tt][2]=0.f; acc[i][tt][3]=0.f;
      }
    run_l1(W1F + (size_t)e * 65536, xsb, w, l, l15, lq, acc);

    const float* b1p = (e < 4) ? (be1 + e * 256) : ba1;
    f32x4 d2 = {0,0,0,0};
    #pragma unroll
    for (int p = 0; p < 2; ++p){
      unsigned char* hb_ = p ? hs1 : hs0;
      {
        int hb = (w + 8 * p) * 16 + lq * 4;     // global h base (strip i=p)
        float4 b4 = *(const float4*)&b1p[hb];
        int lb = (w * 16 + lq * 4) * 2;         // local byte col
        #pragma unroll
        for (int tt = 0; tt < 4; ++tt){
          f16x4 hv = pk4(gelu_fast(acc[p][tt][0] + b4.x),
                         gelu_fast(acc[p][tt][1] + b4.y),
                         gelu_fast(acc[p][tt][2] + b4.z),
                         gelu_fast(acc[p][tt][3] + b4.w));
          int lt = tt * 16 + l15;
          *(f16x4*)(hb_ + lt * 256 + (lb ^ ((lt & 15) << 4))) = hv;
        }
      }
      __syncthreads();   // buf p ready; also orders last-read vs next-write
      if (w < 4){
        #pragma unroll
        for (int k2h = 0; k2h < 4; ++k2h){
          int k2 = 4 * p + k2h;
          f16x8 a2 = *(const f16x8*)&W2F[((size_t)(e * 8 + k2) * 64 + l) * 8];
          f16x8 b2 = *(const f16x8*)(hb_ + tokL * 256 + ((k2h * 64 + lq * 16) ^ key));
          d2 = mfma16(a2, b2, d2);
        }
      }
      // no trailing barrier: next write to this buffer is 2 phases away.
    }

    if (e < 4){
      if (w < 4){
        float gwv = (e == 0) ? gw4.x : (e == 1) ? gw4.y : (e == 2) ? gw4.z : gw4.w;
        #pragma unroll
        for (int r = 0; r < 4; ++r){
          int c = lq * 4 + r;
          float bv = (c < 10) ? be2[e * 10 + c] : 0.0f;
          lacc[r] += gwv * (d2[r] + bv);
        }
      }
    } else {
      if (w < 4){
        size_t t = t0 + tokL;
        #pragma unroll
        for (int r = 0; r < 4; ++r){
          int c = lq * 4 + r;
          if (c < 10)
            out[ALPHA_OFF + t * 10 + c] = softplus_fast(d2[r] + ba2[c]) + 1e-6f;
        }
      }
    }
  }
  // final logits write
  if (w < 4){
    size_t t = t0 + tokL;
    #pragma unroll
    for (int r = 0; r < 4; ++r){
      int c = lq * 4 + r;
      if (c < 10) out[t * 10 + c] = lacc[r];
    }
  }
}

// ---------------------------------------------------------------------------
// refine (R8 version): exact fp32 gate for listed tokens; on selection flip
// also recompute logits (all 4 experts, exact gw).
// ---------------------------------------------------------------------------
__global__ __launch_bounds__(256) void refine_kernel(
    const float* __restrict__ x, const float* __restrict__ Wg1,
    const float* __restrict__ bg1, const float* __restrict__ Wg2,
    const float* __restrict__ bg2,
    const float* __restrict__ We1, const float* __restrict__ be1,
    const float* __restrict__ We2, const float* __restrict__ be2,
    const unsigned int* __restrict__ list, const unsigned int* __restrict__ cntp,
    float* __restrict__ out){
  int cnt = (int)*cntp;
  int l = threadIdx.x & 63;
  int hb = l * 4;
  for (int idx = blockIdx.x * 4 + (threadIdx.x >> 6); idx < cnt;
       idx += gridDim.x * 4){
    unsigned ent = list[idx];
    int t = (int)(ent & 0x3FFFFu);
    int oi1 = (ent >> 18) & 3, oi2 = (ent >> 20) & 3;
    const float* xr = x + (size_t)t * 256;
    float a0 = 0.f, a1 = 0.f, a2 = 0.f, a3 = 0.f;
    #pragma unroll 8
    for (int d = 0; d < 256; ++d){
      float xv = xr[d];
      float4 wv = *(const float4*)&Wg1[d * 256 + hb];
      a0 = fmaf(xv, wv.x, a0); a1 = fmaf(xv, wv.y, a1);
      a2 = fmaf(xv, wv.z, a2); a3 = fmaf(xv, wv.w, a3);
    }
    float4 b4 = *(const float4*)&bg1[hb];
    float g0 = gelu_exact(a0 + b4.x), g1 = gelu_exact(a1 + b4.y);
    float g2 = gelu_exact(a2 + b4.z), g3 = gelu_exact(a3 + b4.w);
    float4 w0 = *(const float4*)&Wg2[(hb + 0) * 4];
    float4 w1 = *(const float4*)&Wg2[(hb + 1) * 4];
    float4 w2 = *(const float4*)&Wg2[(hb + 2) * 4];
    float4 w3 = *(const float4*)&Wg2[(hb + 3) * 4];
    float p0 = g0 * w0.x + g1 * w1.x + g2 * w2.x + g3 * w3.x;
    float p1 = g0 * w0.y + g1 * w1.y + g2 * w2.y + g3 * w3.y;
    float p2 = g0 * w0.z + g1 * w1.z + g2 * w2.z + g3 * w3.z;
    float p3 = g0 * w0.w + g1 * w1.w + g2 * w2.w + g3 * w3.w;
    #pragma unroll
    for (int m = 1; m < 64; m <<= 1){
      p0 += __shfl_xor(p0, m, 64); p1 += __shfl_xor(p1, m, 64);
      p2 += __shfl_xor(p2, m, 64); p3 += __shfl_xor(p3, m, 64);
    }
    float4 gw; float gap; int i1, i2;
    topk4(p0 + bg2[0], p1 + bg2[1], p2 + bg2[2], p3 + bg2[3], gw, gap, i1, i2);
    if (l == 0) *(float4*)&out[GW_OFF + (size_t)t * 4] = gw;
    int oldset = (1 << oi1) | (1 << oi2);
    int newset = (1 << i1) | (1 << i2);
    if (oldset != newset){
      float lg[10];
      #pragma unroll
      for (int c = 0; c < 10; ++c) lg[c] = 0.f;
      for (int e = 0; e < 4; ++e){
        float gwe = (e == 0) ? gw.x : (e == 1) ? gw.y : (e == 2) ? gw.z : gw.w;
        float c0 = 0.f, c1 = 0.f, c2 = 0.f, c3 = 0.f;
        #pragma unroll 8
        for (int d = 0; d < 256; ++d){
          float xv = xr[d];
          float4 wv = *(const float4*)&We1[e * 65536 + d * 256 + hb];
          c0 = fmaf(xv, wv.x, c0); c1 = fmaf(xv, wv.y, c1);
          c2 = fmaf(xv, wv.z, c2); c3 = fmaf(xv, wv.w, c3);
        }
        float4 be = *(const float4*)&be1[e * 256 + hb];
        float h[4];
        h[0] = gelu_exact(c0 + be.x); h[1] = gelu_exact(c1 + be.y);
        h[2] = gelu_exact(c2 + be.z); h[3] = gelu_exact(c3 + be.w);
        #pragma unroll
        for (int r = 0; r < 4; ++r){
          const float* w2p = &We2[e * 2560 + (hb + r) * 10];
          #pragma unroll
          for (int c = 0; c < 10; ++c) lg[c] += gwe * (h[r] * w2p[c]);
        }
      }
      #pragma unroll
      for (int m = 1; m < 64; m <<= 1)
        #pragma unroll
        for (int c = 0; c < 10; ++c) lg[c] += __shfl_xor(lg[c], m, 64);
      if (l == 0){
        #pragma unroll
        for (int c = 0; c < 10; ++c)
          out[(size_t)t * 10 + c] = lg[c] + gw.x * be2[c] + gw.y * be2[10 + c]
                                         + gw.z * be2[20 + c] + gw.w * be2[30 + c];
      }
    }
  }
}

// coalesced deterministic reduce of 4096x4 partials -> load[4]
__global__ void reduce_load(const float* __restrict__ lpart, float* __restrict__ out){
  __shared__ float red[4][4];
  int tid = threadIdx.x;
  const float4* lp = (const float4*)lpart;
  float4 v = {0,0,0,0};
  #pragma unroll
  for (int j = 0; j < 16; ++j){
    float4 t = lp[tid + 256 * j];
    v.x += t.x; v.y += t.y; v.z += t.z; v.w += t.w;
  }
  #pragma unroll
  for (int m = 1; m < 64; m <<= 1){
    v.x += __shfl_xor(v.x, m, 64); v.y += __shfl_xor(v.y, m, 64);
    v.z += __shfl_xor(v.z, m, 64); v.w += __shfl_xor(v.w, m, 64);
  }
  if ((tid & 63) == 0){
    red[tid >> 6][0] = v.x; red[tid >> 6][1] = v.y;
    red[tid >> 6][2] = v.z; red[tid >> 6][3] = v.w;
  }
  __syncthreads();
  if (tid < 4)
    out[LOAD_OFF + tid] = red[0][tid] + red[1][tid] + red[2][tid] + red[3][tid];
}

// ---------------------------------------------------------------------------
extern "C" void kernel_launch(void* const* d_in, const int* in_sizes, int n_in,
                              void* d_out, int out_size, void* d_ws, size_t ws_size,
                              hipStream_t stream){
  const float* x   = (const float*)d_in[0];
  const float* Wg1 = (const float*)d_in[1];
  const float* bg1 = (const float*)d_in[2];
  const float* Wg2 = (const float*)d_in[3];
  const float* bg2 = (const float*)d_in[4];
  const float* We1 = (const float*)d_in[5];
  const float* be1 = (const float*)d_in[6];
  const float* We2 = (const float*)d_in[7];
  const float* be2 = (const float*)d_in[8];
  const float* Wa1 = (const float*)d_in[9];
  const float* ba1 = (const float*)d_in[10];
  const float* Wa2 = (const float*)d_in[11];
  const float* ba2 = (const float*)d_in[12];
  float* out = (float*)d_out;

  _Float16* W1F       = (_Float16*)((char*)d_ws + W1F_OFF);
  _Float16* W2F       = (_Float16*)((char*)d_ws + W2F_OFF);
  unsigned int* cntp  = (unsigned int*)((char*)d_ws + CNT_OFF);
  unsigned int* list  = (unsigned int*)((char*)d_ws + LIST_OFF);
  float* lpart        = (float*)((char*)d_ws + LPART_OFF);

  hipLaunchKernelGGL(prep_w1f, dim3(192), dim3(256), 0, stream, We1, Wa1, Wg1, W1F);
  hipLaunchKernelGGL(prep_w2f, dim3(12),  dim3(256), 0, stream, We2, Wa2, Wg2, W2F, cntp);
  hipLaunchKernelGGL(fused_kernel, dim3(4096), dim3(512), 0, stream,
                     x, W1F, W2F, bg1, Wg2, bg2, be1, be2, ba1, ba2,
                     out, list, cntp, lpart);
  hipLaunchKernelGGL(refine_kernel, dim3(1024), dim3(256), 0, stream,
                     x, Wg1, bg1, Wg2, bg2, We1, be1, We2, be2, list, cntp, out);
  hipLaunchKernelGGL(reduce_load, dim3(1), dim3(256), 0, stream, lpart, out);
}